// Round 2
// baseline (162034.558 us; speedup 1.0000x reference)
//
#include <hip/hip_runtime.h>
#include <math.h>

#define NB 4
#define NS 512
#define ND 512
#define NH 8
#define NHD 64
#define NL 2
#define NFF 2048
#define NV 32000
#define NWG 256
#define ATT_SCALE 0.125f
#define EMB_SCALEF 22.627416997969522f

// ---- LDS weight layout (floats), per-WG slices ----
// oW: 2 layers x 2 cols, stride 513 ; f1W: 2 x 8 cols, stride 520
// f2W: 2 x 2 cols, stride 2049      ; kW/vW: 4 cols, stride 513
#define OW_OFF 0
#define OW_SZ  (2*2*513)
#define F1_OFF (OW_OFF + OW_SZ)
#define F1_SZ  (2*8*520)
#define F2_OFF (F1_OFF + F1_SZ)
#define F2_SZ  (2*2*2049)
#define KV_OFF (F2_OFF + F2_SZ)
#define KV_SZ  (4*513)
#define W_TOTAL (KV_OFF + KV_SZ)   // 20620 floats

struct P {
  const int* ids;
  const float *tok, *pos, *lw, *kW, *kb, *vW, *vb, *qW, *qb, *oW, *ob;
  const float *f1W, *f1b, *f2W, *f2b, *ln1w, *ln1b, *ln2w, *ln2b, *lnfw, *lnfb, *headW;
  float *emb, *memk, *memv, *X, *r1g, *r2g, *ff1g, *attM, *attS, *attO, *kv0k, *kv0v;
  int* bar;
};

// ---- two-level device barrier: 8 leaves x 32 WGs, monotonic counters ----
__device__ __forceinline__ void gbar(int* bar, int iter) {
  __syncthreads();
  if (threadIdx.x == 0) {
    __threadfence();  // release: prior writes visible device-wide
    int li = blockIdx.x & 7;
    int old = __hip_atomic_fetch_add(&bar[li * 32], 1, __ATOMIC_ACQ_REL, __HIP_MEMORY_SCOPE_AGENT);
    if (old == iter * 32 + 31)
      __hip_atomic_fetch_add(&bar[256], 1, __ATOMIC_ACQ_REL, __HIP_MEMORY_SCOPE_AGENT);
    while (__hip_atomic_load(&bar[256], __ATOMIC_ACQUIRE, __HIP_MEMORY_SCOPE_AGENT) < iter * 8 + 8) {}
    __threadfence();  // acquire: invalidate caches, see others' writes
  }
  __syncthreads();
}
#define GBAR() { gbar(p.bar, bar_iter); bar_iter++; }

__device__ __forceinline__ float blk_sum(float v, float* red) {
  #pragma unroll
  for (int o = 32; o > 0; o >>= 1) v += __shfl_down(v, o, 64);
  const int tid = threadIdx.x;
  __syncthreads();
  if ((tid & 63) == 0) red[tid >> 6] = v;
  __syncthreads();
  return red[0] + red[1] + red[2] + red[3];
}
__device__ __forceinline__ float blk_max(float v, float* red) {
  #pragma unroll
  for (int o = 32; o > 0; o >>= 1) v = fmaxf(v, __shfl_down(v, o, 64));
  const int tid = threadIdx.x;
  __syncthreads();
  if ((tid & 63) == 0) red[tid >> 6] = v;
  __syncthreads();
  return fmaxf(fmaxf(red[0], red[1]), fmaxf(red[2], red[3]));
}

__global__ void __launch_bounds__(256, 1) scan_kernel(P p) {
  const int wg = blockIdx.x;
  const int tid = threadIdx.x;
  __shared__ float wds[W_TOTAL];     // 82.5 KB weight slices
  __shared__ float xbuf[4 * 2064];   // 33 KB staging (stride 516 narrow / 2064 wide)
  __shared__ float part[256];
  __shared__ float sc[256];
  __shared__ float fct[128];
  __shared__ float qv[64];
  __shared__ float red[4];
  __shared__ float stm[4], str[4], stm2[4], str2[4], stm3[4], str3[4];
  int bar_iter = 0;

  // ================= setup phase 1: weights -> LDS, embedding =================
  for (int e = tid; e < 2 * 2 * 512; e += 256) {       // oW
    int k = e & 511, c = (e >> 9) & 1, l = e >> 10;
    wds[OW_OFF + (l * 2 + c) * 513 + k] = p.oW[((size_t)l * ND + k) * ND + wg * 2 + c];
  }
  for (int e = tid; e < 2 * 512 * 8; e += 256) {       // f1W
    int c = e & 7, k = (e >> 3) & 511, l = e >> 12;
    wds[F1_OFF + (l * 8 + c) * 520 + k] = p.f1W[((size_t)l * ND + k) * NFF + wg * 8 + c];
  }
  for (int e = tid; e < 2 * 2048 * 2; e += 256) {      // f2W
    int c = e & 1, k = (e >> 1) & 2047, l = e >> 12;
    wds[F2_OFF + (l * 2 + c) * 2049 + k] = p.f2W[((size_t)l * NFF + k) * ND + wg * 2 + c];
  }
  for (int e = tid; e < 512 * 4; e += 256) {           // kW, vW
    int c = e & 3, k = e >> 2;
    const float* W = (c < 2) ? p.kW : p.vW;
    wds[KV_OFF + c * 513 + k] = W[(size_t)k * ND + wg * 2 + (c & 1)];
  }
  for (int i = wg * 256 + tid; i < NB * NS * ND; i += NWG * 256) {
    int d = i & 511, bs = i >> 9, t = bs & 511, b = bs >> 9;
    p.emb[i] = p.tok[(size_t)p.ids[b * NS + t] * ND + d] * EMB_SCALEF + p.pos[t * ND + d];
  }
  GBAR();

  // ================= setup phase 2: q0 for all t (scale folded), kv0 =================
  {
    for (int pass = 0; pass < 2; pass++) {
      int r0 = wg * 8 + pass * 4;                      // row = b*NS + t
      for (int v = tid; v < 4 * 512; v += 256) {
        int rr = v >> 9, k = v & 511;
        xbuf[rr * 516 + k] = p.emb[(size_t)(r0 + rr) * ND + k];
      }
      __syncthreads();
      int j = tid;
      float a0_[4] = {0, 0, 0, 0}, a1_[4] = {0, 0, 0, 0};
      for (int k = 0; k < 512; k++) {
        float w0v = p.qW[(size_t)k * ND + j];
        float w1v = p.qW[(size_t)k * ND + j + 256];
        #pragma unroll
        for (int r = 0; r < 4; r++) {
          float xv = xbuf[r * 516 + k];
          a0_[r] = fmaf(xv, w0v, a0_[r]);
          a1_[r] = fmaf(xv, w1v, a1_[r]);
        }
      }
      float qb0 = p.qb[j], qb1 = p.qb[j + 256];
      #pragma unroll
      for (int r = 0; r < 4; r++) {
        p.X[(size_t)(r0 + r) * ND + j] = (a0_[r] + qb0) * ATT_SCALE;
        p.X[(size_t)(r0 + r) * ND + j + 256] = (a1_[r] + qb1) * ATT_SCALE;
      }
      __syncthreads();
    }
    // kv0 from emb[:,0,:]
    for (int v = tid; v < 4 * 512; v += 256) {
      int b = v >> 9, k = v & 511;
      xbuf[b * 516 + k] = p.emb[((size_t)b * NS) * ND + k];
    }
    __syncthreads();
    {
      int kc = tid & 15, dot = tid >> 4, c = dot & 3, b = dot >> 2;
      const float* wcol = &wds[KV_OFF + c * 513];
      float acc = 0.f;
      #pragma unroll 8
      for (int k = kc; k < 512; k += 16) acc = fmaf(xbuf[b * 516 + k], wcol[k], acc);
      #pragma unroll
      for (int o = 8; o; o >>= 1) acc += __shfl_down(acc, o, 16);
      if (kc == 0) {
        int j = wg * 2 + (c & 1);
        if (c < 2) p.kv0k[b * ND + j] = acc + p.kb[j];
        else       p.kv0v[b * ND + j] = acc + p.vb[j];
      }
    }
  }
  GBAR();

  float w0, w1, w2;
  {
    float a0 = p.lw[0], a1 = p.lw[1], a2 = p.lw[2];
    float mx = fmaxf(a0, fmaxf(a1, a2));
    float e0 = expf(a0 - mx), e1 = expf(a1 - mx), e2 = expf(a2 - mx);
    float inv = 1.f / (e0 + e1 + e2);
    w0 = e0 * inv; w1 = e1 * inv; w2 = e2 * inv;
  }

  // ================= the scan =================
  for (int t = 0; t < NS; t++) {
    const int len = (t == 0) ? 1 : t;

    for (int l = 0; l < NL; l++) {
      // ===== ATT phase: 128 WGs = (b, h, quad); flash partials =====
      if (wg < 128) {
        const int b = wg >> 5, h = (wg >> 2) & 7, qd = wg & 3;
        const int len4 = (len + 3) >> 2;
        const int lo = qd * len4;
        const int hi = min(lo + len4, len);
        const int cnt = hi - lo;

        if (l == 0) {
          if (tid < 64) qv[tid] = p.X[((size_t)b * NS + t) * ND + h * 64 + tid];
          __syncthreads();
        } else {
          // x2_0 = ln2_0(r2_0), then q1 for this head (scale folded)
          float s = 0.f, q = 0.f;
          for (int i = tid; i < 512; i += 256) { float x = p.r2g[b * ND + i]; s += x; q += x * x; }
          s = blk_sum(s, red); q = blk_sum(q, red);
          float mean = s * (1.f / 512), rstd = rsqrtf(q * (1.f / 512) - mean * mean + 1e-5f);
          for (int i = tid; i < 512; i += 256)
            xbuf[i] = (p.r2g[b * ND + i] - mean) * rstd * p.ln2w[i] + p.ln2b[i];
          __syncthreads();
          {
            int d = tid & 63, kc = tid >> 6;
            const float* wq = p.qW + (size_t)ND * ND;
            float acc = 0.f;
            for (int k = kc; k < 512; k += 4)
              acc = fmaf(xbuf[k], wq[(size_t)k * ND + h * 64 + d], acc);
            part[tid] = acc;
            __syncthreads();
            if (tid < 64)
              qv[tid] = (part[tid] + part[64 + tid] + part[128 + tid] + part[192 + tid]
                         + p.qb[ND + h * 64 + tid]) * ATT_SCALE;
            __syncthreads();
          }
        }
        const float* kbase = (t == 0) ? (p.kv0k + b * ND) : (p.memk + (size_t)b * NS * ND);
        const float* vbase = (t == 0) ? (p.kv0v + b * ND) : (p.memv + (size_t)b * NS * ND);
        float s = -1e30f;
        if (tid < cnt) {
          int m = lo + tid;
          const float4* kr4 = (const float4*)(kbase + (size_t)m * ND + h * 64);
          float acc = 0.f;
          #pragma unroll
          for (int i = 0; i < 16; i++) {
            float4 kv4 = kr4[i];
            acc = fmaf(qv[i * 4 + 0], kv4.x, acc);
            acc = fmaf(qv[i * 4 + 1], kv4.y, acc);
            acc = fmaf(qv[i * 4 + 2], kv4.z, acc);
            acc = fmaf(qv[i * 4 + 3], kv4.w, acc);
          }
          s = acc;
        }
        float M = blk_max(s, red);
        float e = (tid < cnt) ? __expf(s - M) : 0.f;
        sc[tid] = e;
        float S = blk_sum(e, red);
        {
          int d = tid & 63, mc = tid >> 6;
          float acc = 0.f;
          for (int m = lo + mc; m < hi; m += 4)
            acc = fmaf(sc[m - lo], vbase[(size_t)m * ND + h * 64 + d], acc);
          part[tid] = acc;
          __syncthreads();
          if (tid < 64)
            p.attO[((b * 8 + h) * 4 + qd) * 64 + tid] =
                part[tid] + part[64 + tid] + part[128 + tid] + part[192 + tid];
          if (tid == 0) { p.attM[(b * 8 + h) * 4 + qd] = M; p.attS[(b * 8 + h) * 4 + qd] = S; }
        }
      }
      GBAR();

      // ===== COMB phase: softmax-merge partials + o-proj + residual =====
      {
        if (tid < 32) {
          float M0 = p.attM[tid * 4 + 0], M1 = p.attM[tid * 4 + 1];
          float M2 = p.attM[tid * 4 + 2], M3 = p.attM[tid * 4 + 3];
          float M = fmaxf(fmaxf(M0, M1), fmaxf(M2, M3));
          float e0 = __expf(M0 - M), e1 = __expf(M1 - M), e2 = __expf(M2 - M), e3 = __expf(M3 - M);
          float den = e0 * p.attS[tid * 4 + 0] + e1 * p.attS[tid * 4 + 1]
                    + e2 * p.attS[tid * 4 + 2] + e3 * p.attS[tid * 4 + 3];
          float inv = 1.f / den;
          fct[tid * 4 + 0] = e0 * inv; fct[tid * 4 + 1] = e1 * inv;
          fct[tid * 4 + 2] = e2 * inv; fct[tid * 4 + 3] = e3 * inv;
        }
        if (l == 1) {  // ln2_0 stats for residual
          int wv = tid >> 6, lane = tid & 63;
          float s = 0.f, q = 0.f;
          for (int i = lane; i < 512; i += 64) { float x = p.r2g[wv * ND + i]; s += x; q += x * x; }
          #pragma unroll
          for (int o = 32; o; o >>= 1) { s += __shfl_down(s, o, 64); q += __shfl_down(q, o, 64); }
          if (lane == 0) {
            float mean = s * (1.f / 512);
            stm2[wv] = mean; str2[wv] = rsqrtf(q * (1.f / 512) - mean * mean + 1e-5f);
          }
        }
        __syncthreads();
        for (int v = tid; v < 2048; v += 256) {
          int b = v >> 9, j = v & 511, h = j >> 6, d = j & 63;
          int bh = b * 8 + h;
          float a = fct[bh * 4 + 0] * p.attO[(bh * 4 + 0) * 64 + d]
                  + fct[bh * 4 + 1] * p.attO[(bh * 4 + 1) * 64 + d]
                  + fct[bh * 4 + 2] * p.attO[(bh * 4 + 2) * 64 + d]
                  + fct[bh * 4 + 3] * p.attO[(bh * 4 + 3) * 64 + d];
          xbuf[b * 516 + j] = a;
        }
        __syncthreads();
        int kc = tid & 31, dot = tid >> 5, c = dot & 1, b = dot >> 1;
        const float* wcol = &wds[OW_OFF + (l * 2 + c) * 513];
        float acc = 0.f;
        #pragma unroll 8
        for (int k = kc; k < 512; k += 32) acc = fmaf(xbuf[b * 516 + k], wcol[k], acc);
        #pragma unroll
        for (int o = 16; o; o >>= 1) acc += __shfl_down(acc, o, 32);
        if (kc == 0) {
          int j = wg * 2 + c;
          float resid;
          if (l == 0) resid = p.emb[((size_t)b * NS + t) * ND + j];
          else        resid = (p.r2g[b * ND + j] - stm2[b]) * str2[b] * p.ln2w[j] + p.ln2b[j];
          p.r1g[(l * NB + b) * ND + j] = resid + acc + p.ob[l * ND + j];
        }
      }
      GBAR();

      // ===== FF1 phase =====
      {
        int wv = tid >> 6, lane = tid & 63;
        float s = 0.f, q = 0.f;
        for (int i = lane; i < 512; i += 64) { float x = p.r1g[(l * NB + wv) * ND + i]; s += x; q += x * x; }
        #pragma unroll
        for (int o = 32; o; o >>= 1) { s += __shfl_down(s, o, 64); q += __shfl_down(q, o, 64); }
        if (lane == 0) {
          float mean = s * (1.f / 512);
          stm[wv] = mean; str[wv] = rsqrtf(q * (1.f / 512) - mean * mean + 1e-5f);
        }
        __syncthreads();
        for (int v = tid; v < 2048; v += 256) {
          int b = v >> 9, i = v & 511;
          xbuf[b * 516 + i] = (p.r1g[(l * NB + b) * ND + i] - stm[b]) * str[b]
                              * p.ln1w[l * ND + i] + p.ln1b[l * ND + i];
        }
        __syncthreads();
        int kc = tid & 7, dot = tid >> 3, c = dot & 7, b = dot >> 3;
        const float* wcol = &wds[F1_OFF + (l * 8 + c) * 520];
        float acc = 0.f;
        #pragma unroll 8
        for (int k = kc; k < 512; k += 8) acc = fmaf(xbuf[b * 516 + k], wcol[k], acc);
        #pragma unroll
        for (int o = 4; o; o >>= 1) acc += __shfl_down(acc, o, 8);
        if (kc == 0) {
          int j = wg * 8 + c;
          p.ff1g[b * NFF + j] = fmaxf(acc + p.f1b[l * NFF + j], 0.f);
        }
      }
      GBAR();

      // ===== FF2 phase =====
      {
        for (int v = tid; v < 4 * 2048; v += 256) {
          int b = v >> 11, k = v & 2047;
          xbuf[b * 2064 + k] = p.ff1g[b * NFF + k];
        }
        __syncthreads();
        int kc = tid & 31, dot = tid >> 5, c = dot & 1, b = dot >> 1;
        const float* wcol = &wds[F2_OFF + (l * 2 + c) * 2049];
        float acc = 0.f;
        #pragma unroll 8
        for (int k = kc; k < 2048; k += 32) acc = fmaf(xbuf[b * 2064 + k], wcol[k], acc);
        #pragma unroll
        for (int o = 16; o; o >>= 1) acc += __shfl_down(acc, o, 32);
        if (kc == 0) {
          int j = wg * 2 + c;
          float x1 = (p.r1g[(l * NB + b) * ND + j] - stm[b]) * str[b]
                     * p.ln1w[l * ND + j] + p.ln1b[l * ND + j];
          p.r2g[(l * NB + b) * ND + j] = x1 + acc + p.f2b[l * ND + j];
        }
      }
      GBAR();
    } // l

    // ===== PM phase: m-combine, hidden write, kv projection, mem write =====
    {
      int wv = tid >> 6, lane = tid & 63;
      for (int pass = 0; pass < 2; pass++) {
        float s = 0.f, q = 0.f;
        for (int i = lane; i < 512; i += 64) { float x = p.r2g[(pass * NB + wv) * ND + i]; s += x; q += x * x; }
        #pragma unroll
        for (int o = 32; o; o >>= 1) { s += __shfl_down(s, o, 64); q += __shfl_down(q, o, 64); }
        if (lane == 0) {
          float mean = s * (1.f / 512), rstd = rsqrtf(q * (1.f / 512) - mean * mean + 1e-5f);
          if (pass == 0) { stm2[wv] = mean; str2[wv] = rstd; }
          else           { stm3[wv] = mean; str3[wv] = rstd; }
        }
      }
      __syncthreads();
      for (int v = tid; v < 2048; v += 256) {
        int b = v >> 9, j = v & 511;
        float e = p.emb[((size_t)b * NS + t) * ND + j];
        float x20 = (p.r2g[b * ND + j] - stm2[b]) * str2[b] * p.ln2w[j] + p.ln2b[j];
        float x21 = (p.r2g[(NB + b) * ND + j] - stm3[b]) * str3[b] * p.ln2w[ND + j] + p.ln2b[ND + j];
        xbuf[b * 516 + j] = w0 * e + w1 * x20 + w2 * x21;
        if (wg == b) p.X[((size_t)b * NS + t) * ND + j] = x21;   // hidden (aliases consumed q0)
      }
      __syncthreads();
      int kc = tid & 15, dot = tid >> 4, c = dot & 3, b = dot >> 2;
      const float* wcol = &wds[KV_OFF + c * 513];
      float acc = 0.f;
      #pragma unroll 8
      for (int k = kc; k < 512; k += 16) acc = fmaf(xbuf[b * 516 + k], wcol[k], acc);
      #pragma unroll
      for (int o = 8; o; o >>= 1) acc += __shfl_down(acc, o, 16);
      if (kc == 0) {
        int j = wg * 2 + (c & 1);
        if (c < 2) p.memk[((size_t)b * NS + t) * ND + j] = acc + p.kb[j];
        else       p.memv[((size_t)b * NS + t) * ND + j] = acc + p.vb[j];
      }
    }
    GBAR();
  } // t
}

// ---- final layernorm ----
__global__ void __launch_bounds__(256) lnf_kernel(const float* __restrict__ hidden,
                                                  const float* __restrict__ w,
                                                  const float* __restrict__ bi,
                                                  float* __restrict__ out) {
  __shared__ float red[4];
  const int row = blockIdx.x;
  const float* x = hidden + (size_t)row * ND;
  const int tid = threadIdx.x;
  float s = 0.f, q = 0.f;
  for (int i = tid; i < ND; i += 256) { float v = x[i]; s += v; q += v * v; }
  s = blk_sum(s, red);
  q = blk_sum(q, red);
  float mean = s * (1.0f / ND);
  float rstd = rsqrtf(q * (1.0f / ND) - mean * mean + 1e-5f);
  for (int i = tid; i < ND; i += 256)
    out[(size_t)row * ND + i] = (x[i] - mean) * rstd * w[i] + bi[i];
}

// ---- head GEMM: C[2048,32000] = A[2048,512] @ W[512,32000], fp32 ----
__global__ void __launch_bounds__(256) head_gemm(const float* __restrict__ A,
                                                 const float* __restrict__ Bw,
                                                 float* __restrict__ C) {
  __shared__ float As[8][128];
  __shared__ float Bs[8][128];
  const int tid = threadIdx.x;
  const int col0 = blockIdx.x * 128;
  const int row0 = blockIdx.y * 128;
  const int tx = tid & 15, ty = tid >> 4;
  float acc[8][8] = {};

  for (int k0 = 0; k0 < 512; k0 += 8) {
    {
      int r = tid >> 1, kk = (tid & 1) * 4;
      const float4 v = *(const float4*)(A + (size_t)(row0 + r) * 512 + k0 + kk);
      As[kk + 0][r] = v.x; As[kk + 1][r] = v.y; As[kk + 2][r] = v.z; As[kk + 3][r] = v.w;
      int brr = tid >> 5, bcc = (tid & 31) * 4;
      *(float4*)&Bs[brr][bcc] = *(const float4*)(Bw + (size_t)(k0 + brr) * NV + col0 + bcc);
    }
    __syncthreads();
    #pragma unroll
    for (int kk = 0; kk < 8; kk++) {
      float a[8], bv[8];
      #pragma unroll
      for (int i = 0; i < 8; i++) a[i] = As[kk][ty * 8 + i];
      #pragma unroll
      for (int j = 0; j < 8; j++) bv[j] = Bs[kk][tx * 8 + j];
      #pragma unroll
      for (int i = 0; i < 8; i++)
        #pragma unroll
        for (int j = 0; j < 8; j++) acc[i][j] = fmaf(a[i], bv[j], acc[i][j]);
    }
    __syncthreads();
  }
  #pragma unroll
  for (int i = 0; i < 8; i++) {
    float* cp = C + (size_t)(row0 + ty * 8 + i) * NV + col0 + tx * 8;
    float4 v0 = {acc[i][0], acc[i][1], acc[i][2], acc[i][3]};
    float4 v1 = {acc[i][4], acc[i][5], acc[i][6], acc[i][7]};
    *(float4*)cp = v0;
    *(float4*)(cp + 4) = v1;
  }
}

extern "C" void kernel_launch(void* const* d_in, const int* in_sizes, int n_in,
                              void* d_out, int out_size, void* d_ws, size_t ws_size,
                              hipStream_t stream) {
  P p;
  p.ids  = (const int*)d_in[0];
  p.tok  = (const float*)d_in[1];
  p.pos  = (const float*)d_in[2];
  p.lw   = (const float*)d_in[3];
  p.kW   = (const float*)d_in[4];
  p.kb   = (const float*)d_in[5];
  p.vW   = (const float*)d_in[6];
  p.vb   = (const float*)d_in[7];
  p.qW   = (const float*)d_in[8];
  p.qb   = (const float*)d_in[9];
  p.oW   = (const float*)d_in[10];
  p.ob   = (const float*)d_in[11];
  p.f1W  = (const float*)d_in[12];
  p.f1b  = (const float*)d_in[13];
  p.f2W  = (const float*)d_in[14];
  p.f2b  = (const float*)d_in[15];
  p.ln1w = (const float*)d_in[16];
  p.ln1b = (const float*)d_in[17];
  p.ln2w = (const float*)d_in[18];
  p.ln2b = (const float*)d_in[19];
  p.lnfw = (const float*)d_in[20];
  p.lnfb = (const float*)d_in[21];
  p.headW = (const float*)d_in[22];

  float* ws = (float*)d_ws;
  p.emb  = ws;
  p.memk = ws + 1048576;
  p.memv = ws + 2097152;
  p.X    = ws + 3145728;          // q0 during scan, overwritten by hidden
  float* base = ws + 4194304;
  p.kv0k = base;  base += 2048;
  p.kv0v = base;  base += 2048;
  p.r1g  = base;  base += 4096;
  p.r2g  = base;  base += 4096;
  p.ff1g = base;  base += 8192;
  p.attM = base;  base += 128;
  p.attS = base;  base += 128;
  p.attO = base;  base += 8192;
  p.bar  = (int*)base;

  hipMemsetAsync(p.bar, 0, 512 * sizeof(int), stream);
  void* args[] = { &p };
  hipLaunchCooperativeKernel((void*)scan_kernel, dim3(NWG), dim3(256), args, 0, stream);

  lnf_kernel<<<dim3(NB * NS), dim3(256), 0, stream>>>(p.X, p.lnfw, p.lnfb, p.emb);
  head_gemm<<<dim3(NV / 128, (NB * NS) / 128), dim3(256), 0, stream>>>(p.emb, p.headW, (float*)d_out);
}